// Round 3
// baseline (569.739 us; speedup 1.0000x reference)
//
#include <hip/hip_runtime.h>
#include <hip/hip_bf16.h>
#include <math.h>

// Problem constants (from reference)
#define B_ 4
#define S_ 2048
#define D_ 2048
#define H_ 4096
#define M_ (B_*S_)   // 8192 rows for both GEMMs

// Segmented recurrence: 16 segments x 128 steps, 48-step warmup.
#define SEG 128
#define WARM 48
#define P_ (S_/SEG)   // 16

typedef __bf16 bf16x8 __attribute__((ext_vector_type(8)));
typedef float f32x4 __attribute__((ext_vector_type(4)));

__device__ __forceinline__ float bf2f(unsigned short v) {
    union { unsigned u; float f; } x; x.u = ((unsigned)v) << 16; return x.f;
}
__device__ __forceinline__ unsigned short f2bf(float f) {
    union { float f; unsigned u; } x; x.f = f;
    unsigned u = x.u;
    unsigned r = (u + 0x7fffu + ((u >> 16) & 1u)) >> 16;  // RNE
    return (unsigned short)r;
}

__device__ __forceinline__ float fast_exp2(float x) {
#if __has_builtin(__builtin_amdgcn_exp2f)
    return __builtin_amdgcn_exp2f(x);
#else
    return __builtin_exp2f(x);
#endif
}
__device__ __forceinline__ float fast_rcp(float x) {
    return __builtin_amdgcn_rcpf(x);
}

// ---------------- fp32 -> bf16 conversion (8 elems/thread) ----------------
__global__ void cvt_f32_bf16(const float* __restrict__ in,
                             unsigned short* __restrict__ out, int n) {
    int i = (blockIdx.x * blockDim.x + threadIdx.x) * 8;
    if (i >= n) return;
    float4 a = *(const float4*)(in + i);
    float4 b = *(const float4*)(in + i + 4);
    ushort4 o0; o0.x = f2bf(a.x); o0.y = f2bf(a.y); o0.z = f2bf(a.z); o0.w = f2bf(a.w);
    ushort4 o1; o1.x = f2bf(b.x); o1.y = f2bf(b.y); o1.z = f2bf(b.z); o1.w = f2bf(b.w);
    *(ushort4*)(out + i) = o0;
    *(ushort4*)(out + i + 4) = o1;
}

// ---------------- async global->LDS 16B copy ----------------
__device__ __forceinline__ void async_cp16(const unsigned short* g, unsigned short* l) {
    __builtin_amdgcn_global_load_lds(
        (__attribute__((address_space(1))) void*)g,
        (__attribute__((address_space(3))) void*)l,
        16, 0, 0);
}

// Raw barrier (no vmcnt drain) + sched pin: keeps pre-barrier memory ops from
// sinking and MFMA from hoisting above it, but leaves the post-MFMA region
// free so next-phase ds_reads can interleave among MFMAs.
__device__ __forceinline__ void bar_pin() {
    asm volatile("" ::: "memory");
    __builtin_amdgcn_s_barrier();
    asm volatile("" ::: "memory");
    __builtin_amdgcn_sched_barrier(0);
}

template<int N>
__device__ __forceinline__ void wait_vmcnt() {
    if constexpr (N == 0)      asm volatile("s_waitcnt vmcnt(0)" ::: "memory");
    else if constexpr (N == 4) asm volatile("s_waitcnt vmcnt(4)" ::: "memory");
    else if constexpr (N == 6) asm volatile("s_waitcnt vmcnt(6)" ::: "memory");
}

// ---------------- 256x256 8-phase GEMM (B^T layout), 1 barrier/phase ----------------
// C[m,n] = sum_k A[m,k]*Bw[n,k] + bias[n]
// LDS: [buf][mat(A/B)][khalf][256 rows x 32 shorts] = 4 x 32KB = 128 KiB.
// Half-tile g: tau=g>>2, mat=g&1, kh=(g>>1)&1. Staging stream runs 5 halves
// ahead of consumption -> steady-state vmcnt(6), never 0 in the main loop.
// (Lead 5 is MAXIMAL: lead 6 would issue the overwrite of a region in the
// same inter-barrier window as its previous readers' in-flight ds_reads.)
// SINGLE barrier per phase (pre-MFMA). Hazard audit (wave skew <= 1 barrier):
//  RAW: region staged by all waves is vmcnt-retired by each wave BEFORE a
//       barrier that every reader passes before issuing its ds_reads.
//  WAR: earliest same-buffer overwrite (P3 stages tile t+2 kh0) is issued
//       after bar(P2); every reader of that region forced lgkm-completion of
//       its reads (via its own MFMA issue) before arriving at bar(P2). Safe.
// T2 swizzle: row bits[2:1] XOR'd into 16B-granule bits of the byte offset;
// gload_lds writes linearly so the SOURCE address carries the inverse perm;
// ds_read applies the same XOR (involution). Measured: bank conflicts = 0.

__device__ __forceinline__
void stage_half(int g, int G, unsigned short (&lds)[2][2][2][8192],
                const unsigned short* Asrc, const unsigned short* Bsrc,
                int K, int sdst)
{
    if (g >= G) return;
    const int tau = g >> 2;
    const int mat = g & 1;
    const int kh  = (g >> 1) & 1;
    const unsigned short* src = (mat ? Bsrc : Asrc) + (size_t)tau * 64 + kh * 32;
    unsigned short* dst = &lds[tau & 1][mat][kh][sdst];
    async_cp16(src, dst);
    async_cp16(src + (size_t)128 * K, dst + 4096);
}

__device__ __forceinline__
void mfma16(const bf16x8* a, const bf16x8* b, f32x4 (*acc)[4]) {
#pragma unroll
    for (int i = 0; i < 4; ++i)
#pragma unroll
        for (int j = 0; j < 4; ++j)
            acc[i][j] = __builtin_amdgcn_mfma_f32_16x16x32_bf16(
                a[i], b[j], acc[i][j], 0, 0, 0);
}

// One K-tile (BK=64) = 4 phases. Phase p:
//   [ds_read frags | issue 1 half-tile prefetch | optional vmcnt] -> barrier
//   -> setprio(1) 16 MFMA setprio(0)
// vmcnt before the barrier of P1 (validates this tile's kh1, read at P2/P3)
// and P3 (validates next tile's kh0, read at its P0/P1).
template<int BUF, int VP1, int VP3>
__device__ __forceinline__
void do_tile(int t, int G, unsigned short (&lds)[2][2][2][8192],
             const unsigned short* Asrc, const unsigned short* Bsrc, int K,
             int sdst, int aoff, int boff, f32x4 (*acc)[4])
{
    const int g0 = 4 * t + 5;
    bf16x8 a[4], b[4];

    // ---- Phase 0: k-slice 0, M-frags 0-3 (B ks0 loaded, reused in P1) ----
#pragma unroll
    for (int j = 0; j < 4; ++j)
        b[j] = *(const bf16x8*)(&lds[BUF][1][0][boff + j * 512]);
#pragma unroll
    for (int i = 0; i < 4; ++i)
        a[i] = *(const bf16x8*)(&lds[BUF][0][0][aoff + i * 512]);
    stage_half(g0 + 0, G, lds, Asrc, Bsrc, K, sdst);
    bar_pin();
    __builtin_amdgcn_s_setprio(1);
    mfma16(a, b, acc);
    __builtin_amdgcn_s_setprio(0);

    // ---- Phase 1: k-slice 0, M-frags 4-7 ----
#pragma unroll
    for (int i = 0; i < 4; ++i)
        a[i] = *(const bf16x8*)(&lds[BUF][0][0][aoff + (i + 4) * 512]);
    stage_half(g0 + 1, G, lds, Asrc, Bsrc, K, sdst);
    wait_vmcnt<VP1>();
    bar_pin();
    __builtin_amdgcn_s_setprio(1);
    mfma16(a, b, acc + 4);
    __builtin_amdgcn_s_setprio(0);

    // ---- Phase 2: k-slice 1, M-frags 0-3 ----
#pragma unroll
    for (int j = 0; j < 4; ++j)
        b[j] = *(const bf16x8*)(&lds[BUF][1][1][boff + j * 512]);
#pragma unroll
    for (int i = 0; i < 4; ++i)
        a[i] = *(const bf16x8*)(&lds[BUF][0][1][aoff + i * 512]);
    stage_half(g0 + 2, G, lds, Asrc, Bsrc, K, sdst);
    bar_pin();
    __builtin_amdgcn_s_setprio(1);
    mfma16(a, b, acc);
    __builtin_amdgcn_s_setprio(0);

    // ---- Phase 3: k-slice 1, M-frags 4-7 ----
#pragma unroll
    for (int i = 0; i < 4; ++i)
        a[i] = *(const bf16x8*)(&lds[BUF][0][1][aoff + (i + 4) * 512]);
    stage_half(g0 + 3, G, lds, Asrc, Bsrc, K, sdst);
    if constexpr (VP3 >= 0) wait_vmcnt<VP3>();
    bar_pin();
    __builtin_amdgcn_s_setprio(1);
    mfma16(a, b, acc + 4);
    __builtin_amdgcn_s_setprio(0);
}

template<bool OUT_BF16>
__device__ __forceinline__
void gemm256_body(const unsigned short* __restrict__ A,
                  const unsigned short* __restrict__ Bw,
                  const float* __restrict__ bias,
                  unsigned short* __restrict__ outB,
                  float* __restrict__ outF,
                  int M, int N, int K)
{
    __shared__ __align__(16) unsigned short lds[2][2][2][8192];  // 128 KiB

    const int tid  = threadIdx.x;
    const int lane = tid & 63;
    const int wave = tid >> 6;
    const int wm = wave >> 2;          // 0..1: 128-row half of C-tile
    const int wn = wave & 3;           // 0..3: 64-col slice of C-tile
    const int row0 = blockIdx.y * 256;
    const int col0 = blockIdx.x * 256;
    const int NT = K >> 6;             // K/64 (even: 32 or 64)
    const int G  = NT << 2;

    // staging: thread's linear LDS slot -> inverse-swizzled global source col
    const int srow = tid >> 2;                                  // 0..127 (+128 for j=1)
    const int scol = ((tid & 3) ^ ((tid >> 3) & 3)) * 8;        // inverse st-swizzle
    const unsigned short* Asrc = A  + (size_t)(row0 + srow) * K + scol;
    const unsigned short* Bsrc = Bw + (size_t)(col0 + srow) * K + scol;
    const int sdst = tid * 8;

    // ds_read fragment offsets (swizzled; row bits[2:1] == laneM bits[2:1])
    const int laneM = lane & 15;
    const int laneK = (lane >> 4) * 8;
    const int swz   = ((laneM >> 1) & 3) << 3;
    const int aoff  = (((wm * 128 + laneM) * 32 + laneK)) ^ swz;
    const int boff  = (((wn * 64  + laneM) * 32 + laneK)) ^ swz;

    f32x4 acc[8][4];
#pragma unroll
    for (int i = 0; i < 8; ++i)
#pragma unroll
        for (int j = 0; j < 4; ++j)
            acc[i][j] = (f32x4){0.f, 0.f, 0.f, 0.f};

    // prologue: issue tile0 halves (g0-3) + tile1 A-kh0 (g4); vmcnt(6) retires
    // g0,g1 (tile0 kh0 A+B) leaving 3 halves in flight -> steady state.
    stage_half(0, G, lds, Asrc, Bsrc, K, sdst);
    stage_half(1, G, lds, Asrc, Bsrc, K, sdst);
    stage_half(2, G, lds, Asrc, Bsrc, K, sdst);
    stage_half(3, G, lds, Asrc, Bsrc, K, sdst);
    stage_half(4, G, lds, Asrc, Bsrc, K, sdst);
    wait_vmcnt<6>();
    bar_pin();

    int t = 0;
    for (; t < NT - 2; t += 2) {
        do_tile<0, 6, 6>(t,     G, lds, Asrc, Bsrc, K, sdst, aoff, boff, acc);
        do_tile<1, 6, 6>(t + 1, G, lds, Asrc, Bsrc, K, sdst, aoff, boff, acc);
    }
    // tail: staging stream caps at G -> drain 6 -> 4 -> 0
    do_tile<0, 6, 4>(NT - 2, G, lds, Asrc, Bsrc, K, sdst, aoff, boff, acc);
    do_tile<1, 0, -1>(NT - 1, G, lds, Asrc, Bsrc, K, sdst, aoff, boff, acc);

    // epilogue: C/D layout (verified m89/m91): m-row = (lane>>4)*4 + rr, n-col = lane&15
    const int rQ = (lane >> 4) * 4;
#pragma unroll
    for (int j = 0; j < 4; ++j) {
        const int n = col0 + wn * 64 + j * 16 + laneM;
        const float bv = bias[n];
#pragma unroll
        for (int i = 0; i < 8; ++i) {
#pragma unroll
            for (int rr = 0; rr < 4; ++rr) {
                const int m = row0 + wm * 128 + i * 16 + rQ + rr;
                const float v = acc[i][j][rr] + bv;
                if (OUT_BF16) outB[(size_t)m * N + n] = f2bf(v);
                else          outF[(size_t)m * N + n] = v;
            }
        }
    }
}

__global__ __launch_bounds__(512, 2)
void gemm_u(const unsigned short* __restrict__ A, const unsigned short* __restrict__ Bw,
            const float* __restrict__ bias, unsigned short* __restrict__ outB,
            int M, int N, int K) {
    gemm256_body<true>(A, Bw, bias, outB, nullptr, M, N, K);
}
__global__ __launch_bounds__(512, 2)
void gemm_y(const unsigned short* __restrict__ A, const unsigned short* __restrict__ Bw,
            const float* __restrict__ bias, float* __restrict__ outF,
            int M, int N, int K) {
    gemm256_body<false>(A, Bw, bias, nullptr, outF, M, N, K);
}

// ---------------- segmented-parallel tanh recurrence ----------------
__global__ __launch_bounds__(256)
void recur_seg(const unsigned short* __restrict__ u,
               const float* __restrict__ gamma,
               const float* __restrict__ beta,
               unsigned short* __restrict__ st)
{
    const int tid = blockIdx.x * 256 + threadIdx.x;   // [0, P_*B_*H_)
    const int h   = tid & (H_ - 1);
    const int b   = (tid >> 12) & (B_ - 1);
    const int seg = tid >> 14;
    const int s0  = seg * SEG;
    const int sw  = (seg == 0) ? 0 : s0 - WARM;
    const int nst = s0 + SEG - sw;                    // 128 or 176 (both %16==0)
    const float K2  = 2.885390082f;                   // 2*log2(e)
    const float gk  = gamma[h] * K2;
    const float bek = beta[h]  * K2;
    float state = 0.f;

    size_t idx = ((size_t)b * S_ + sw) * H_ + h;
    float cur[16], nxt[16];
    #pragma unroll
    for (int k = 0; k < 16; ++k) cur[k] = bf2f(u[idx + (size_t)k * H_]);

    int s = sw;
    const int ngroups = nst >> 4;
    for (int g = 0; g < ngroups; ++g) {
        const size_t nidx = idx + (size_t)16 * H_;
        if (g + 1 < ngroups) {
            #pragma unroll
            for (int k = 0; k < 16; ++k) nxt[k] = bf2f(u[nidx + (size_t)k * H_]);
        }
        #pragma unroll
        for (int k = 0; k < 16; ++k) {
            const float c = fmaf(cur[k], K2, bek);    // off-chain
            const float t = fmaf(state, gk, c);       // chain: fma
            const float e = fast_exp2(t);             // chain: v_exp_f32
            const float rr = fast_rcp(1.0f + e);      // chain: add + v_rcp_f32
            state = fmaf(-2.0f, rr, 1.0f);            // chain: fma
            if (s + k >= s0) st[idx + (size_t)k * H_] = f2bf(state);
        }
        idx = nidx; s += 16;
        #pragma unroll
        for (int k = 0; k < 16; ++k) cur[k] = nxt[k];
    }
}

extern "C" void kernel_launch(void* const* d_in, const int* in_sizes, int n_in,
                              void* d_out, int out_size, void* d_ws, size_t ws_size,
                              hipStream_t stream) {
    const float* x     = (const float*)d_in[0];  // [B,S,D]
    const float* W_in  = (const float*)d_in[1];  // [H,D]
    const float* b_in  = (const float*)d_in[2];  // [H]
    const float* W_out = (const float*)d_in[3];  // [D,H]
    const float* b_out = (const float*)d_in[4];  // [D]
    const float* gamma = (const float*)d_in[5];  // [H]
    const float* beta  = (const float*)d_in[6];  // [H]
    float* y = (float*)d_out;                    // [B,S,D] fp32

    // workspace layout (bf16 buffers), total ~192 MiB
    unsigned short* x_b    = (unsigned short*)d_ws;              // M*D
    unsigned short* win_b  = x_b    + (size_t)M_ * D_;           // H*D
    unsigned short* wout_b = win_b  + (size_t)H_ * D_;           // D*H
    unsigned short* u_b    = wout_b + (size_t)D_ * H_;           // M*H
    unsigned short* st_b   = u_b    + (size_t)M_ * H_;           // M*H

    // convert inputs to bf16
    cvt_f32_bf16<<<(M_ * D_) / 2048, 256, 0, stream>>>(x,     x_b,    M_ * D_);
    cvt_f32_bf16<<<(H_ * D_) / 2048, 256, 0, stream>>>(W_in,  win_b,  H_ * D_);
    cvt_f32_bf16<<<(D_ * H_) / 2048, 256, 0, stream>>>(W_out, wout_b, D_ * H_);

    // u = x @ W_in^T + b_in   -> bf16 [M,H]   grid: (cols, rows), 256x256 tiles
    dim3 g1(H_ / 256, M_ / 256);
    gemm_u<<<g1, 512, 0, stream>>>(x_b, win_b, b_in, u_b, M_, H_, D_);

    // segmented-parallel recurrence -> states bf16 [M,H]
    recur_seg<<<(P_ * B_ * H_) / 256, 256, 0, stream>>>(u_b, gamma, beta, st_b);

    // y = states @ W_out^T + b_out -> fp32 [M,D]   grid: (cols, rows)
    dim3 g2(D_ / 256, M_ / 256);
    gemm_y<<<g2, 512, 0, stream>>>(st_b, wout_b, b_out, y, M_, D_, H_);
}

// Round 5
// 484.032 us; speedup vs baseline: 1.1771x; 1.1771x over previous
//
#include <hip/hip_runtime.h>
#include <hip/hip_bf16.h>
#include <math.h>

// Problem constants (from reference)
#define B_ 4
#define S_ 2048
#define D_ 2048
#define H_ 4096
#define M_ (B_*S_)   // 8192 rows for both GEMMs

// Segmented recurrence: 16 segments x 128 steps, 48-step warmup.
#define SEG 128
#define WARM 48
#define P_ (S_/SEG)   // 16

typedef __bf16 bf16x8 __attribute__((ext_vector_type(8)));
typedef float f32x4 __attribute__((ext_vector_type(4)));

__device__ __forceinline__ float bf2f(unsigned short v) {
    union { unsigned u; float f; } x; x.u = ((unsigned)v) << 16; return x.f;
}
__device__ __forceinline__ unsigned short f2bf(float f) {
    union { float f; unsigned u; } x; x.f = f;
    unsigned u = x.u;
    unsigned r = (u + 0x7fffu + ((u >> 16) & 1u)) >> 16;  // RNE
    return (unsigned short)r;
}

__device__ __forceinline__ float fast_exp2(float x) {
#if __has_builtin(__builtin_amdgcn_exp2f)
    return __builtin_amdgcn_exp2f(x);
#else
    return __builtin_exp2f(x);
#endif
}
__device__ __forceinline__ float fast_rcp(float x) {
    return __builtin_amdgcn_rcpf(x);
}

// ---------------- fp32 -> bf16 conversion (8 elems/thread) ----------------
__global__ void cvt_f32_bf16(const float* __restrict__ in,
                             unsigned short* __restrict__ out, int n) {
    int i = (blockIdx.x * blockDim.x + threadIdx.x) * 8;
    if (i >= n) return;
    float4 a = *(const float4*)(in + i);
    float4 b = *(const float4*)(in + i + 4);
    ushort4 o0; o0.x = f2bf(a.x); o0.y = f2bf(a.y); o0.z = f2bf(a.z); o0.w = f2bf(a.w);
    ushort4 o1; o1.x = f2bf(b.x); o1.y = f2bf(b.y); o1.z = f2bf(b.z); o1.w = f2bf(b.w);
    *(ushort4*)(out + i) = o0;
    *(ushort4*)(out + i + 4) = o1;
}

// ---------------- async global->LDS 16B copy ----------------
__device__ __forceinline__ void async_cp16(const unsigned short* g, unsigned short* l) {
    __builtin_amdgcn_global_load_lds(
        (__attribute__((address_space(1))) void*)g,
        (__attribute__((address_space(3))) void*)l,
        16, 0, 0);
}

// Raw barrier with compiler-only memory fence (NO vmcnt(0) drain — counted
// vmcnt keeps staging loads in flight across barriers). NO sched_barrier:
// round-3 A/B showed sched pinning regressed (28% vs 35% MfmaUtil, m141-like).
__device__ __forceinline__ void fence_bar() {
    asm volatile("" ::: "memory");
    __builtin_amdgcn_s_barrier();
    asm volatile("" ::: "memory");
}

template<int N>
__device__ __forceinline__ void wait_vmcnt() {
    if constexpr (N == 0)      asm volatile("s_waitcnt vmcnt(0)" ::: "memory");
    else if constexpr (N == 4) asm volatile("s_waitcnt vmcnt(4)" ::: "memory");
    else if constexpr (N == 6) asm volatile("s_waitcnt vmcnt(6)" ::: "memory");
}

// T1: XCD-aware bijective chunked remap (grids here are multiples of 8).
// Natural id = by*gx + bx (row-major over tiles). Each XCD gets a contiguous
// run of natural ids -> row-neighbor tiles share A/B panels in the same L2.
__device__ __forceinline__ void xcd_remap(int& bx, int& by, int gx, int gy) {
    const int nwg = gx * gy;
    const int wg  = by * gx + bx;
    const int cpx = nwg >> 3;                    // nwg % 8 == 0 guaranteed
    const int nid = (wg & 7) * cpx + (wg >> 3);  // bijective since 8 | nwg
    bx = nid % gx;
    by = nid / gx;
}

// ---------------- 256x256 8-phase GEMM (B^T layout), 2 barriers/phase ----------------
// C[m,n] = sum_k A[m,k]*Bw[n,k] + bias[n]
// LDS: [buf][mat(A/B)][khalf][256 rows x 32 shorts] = 4 x 32KB = 128 KiB.
// Half-tile g: tau=g>>2, mat=g&1, kh=(g>>1)&1. Staging stream runs 5 halves
// ahead of consumption -> steady-state vmcnt(6) (3 halves in flight), never
// vmcnt(0) in the main loop. Lead 5 is maximal for the 4-region dbuf (WAR).
// This is the ROUND-1 verified structure (486 us total, gemm ~162 us, 848 TF,
// bank conflicts = 0). Round-3's 1-barrier + sched_barrier variant REGRESSED
// (MfmaUtil 35->28) and is reverted.
// T2 swizzle: row bits[2:1] XOR'd into 16B-granule bits of the byte offset;
// gload_lds writes linearly so the SOURCE address carries the inverse perm;
// ds_read applies the same XOR (involution). Measured: bank conflicts = 0.

__device__ __forceinline__
void stage_half(int g, int G, unsigned short (&lds)[2][2][2][8192],
                const unsigned short* Asrc, const unsigned short* Bsrc,
                int K, int sdst)
{
    if (g >= G) return;
    const int tau = g >> 2;
    const int mat = g & 1;
    const int kh  = (g >> 1) & 1;
    const unsigned short* src = (mat ? Bsrc : Asrc) + (size_t)tau * 64 + kh * 32;
    unsigned short* dst = &lds[tau & 1][mat][kh][sdst];
    async_cp16(src, dst);
    async_cp16(src + (size_t)128 * K, dst + 4096);
}

__device__ __forceinline__
void mfma16(const bf16x8* a, const bf16x8* b, f32x4 (*acc)[4]) {
#pragma unroll
    for (int i = 0; i < 4; ++i)
#pragma unroll
        for (int j = 0; j < 4; ++j)
            acc[i][j] = __builtin_amdgcn_mfma_f32_16x16x32_bf16(
                a[i], b[j], acc[i][j], 0, 0, 0);
}

// One K-tile (BK=64) = 4 phases. Phase p:
//   [ds_read frags | issue 1 half-tile prefetch | optional vmcnt] -> barrier
//   -> setprio(1) 16 MFMA setprio(0) -> barrier
// vmcnt before the pre-MFMA barrier of P1 (validates this tile's kh1, read at
// P2/P3) and P3 (validates next tile's kh0, read at its P0/P1).
template<int BUF, int VP1, int VP3>
__device__ __forceinline__
void do_tile(int t, int G, unsigned short (&lds)[2][2][2][8192],
             const unsigned short* Asrc, const unsigned short* Bsrc, int K,
             int sdst, int aoff, int boff, f32x4 (*acc)[4])
{
    const int g0 = 4 * t + 5;
    bf16x8 a[4], b[4];

    // ---- Phase 0: k-slice 0, M-frags 0-3 (B ks0 loaded, reused in P1) ----
#pragma unroll
    for (int j = 0; j < 4; ++j)
        b[j] = *(const bf16x8*)(&lds[BUF][1][0][boff + j * 512]);
#pragma unroll
    for (int i = 0; i < 4; ++i)
        a[i] = *(const bf16x8*)(&lds[BUF][0][0][aoff + i * 512]);
    stage_half(g0 + 0, G, lds, Asrc, Bsrc, K, sdst);
    fence_bar();
    __builtin_amdgcn_s_setprio(1);
    mfma16(a, b, acc);
    __builtin_amdgcn_s_setprio(0);
    fence_bar();

    // ---- Phase 1: k-slice 0, M-frags 4-7 ----
#pragma unroll
    for (int i = 0; i < 4; ++i)
        a[i] = *(const bf16x8*)(&lds[BUF][0][0][aoff + (i + 4) * 512]);
    stage_half(g0 + 1, G, lds, Asrc, Bsrc, K, sdst);
    wait_vmcnt<VP1>();
    fence_bar();
    __builtin_amdgcn_s_setprio(1);
    mfma16(a, b, acc + 4);
    __builtin_amdgcn_s_setprio(0);
    fence_bar();

    // ---- Phase 2: k-slice 1, M-frags 0-3 ----
#pragma unroll
    for (int j = 0; j < 4; ++j)
        b[j] = *(const bf16x8*)(&lds[BUF][1][1][boff + j * 512]);
#pragma unroll
    for (int i = 0; i < 4; ++i)
        a[i] = *(const bf16x8*)(&lds[BUF][0][1][aoff + i * 512]);
    stage_half(g0 + 2, G, lds, Asrc, Bsrc, K, sdst);
    fence_bar();
    __builtin_amdgcn_s_setprio(1);
    mfma16(a, b, acc);
    __builtin_amdgcn_s_setprio(0);
    fence_bar();

    // ---- Phase 3: k-slice 1, M-frags 4-7 ----
#pragma unroll
    for (int i = 0; i < 4; ++i)
        a[i] = *(const bf16x8*)(&lds[BUF][0][1][aoff + (i + 4) * 512]);
    stage_half(g0 + 3, G, lds, Asrc, Bsrc, K, sdst);
    if constexpr (VP3 >= 0) wait_vmcnt<VP3>();
    fence_bar();
    __builtin_amdgcn_s_setprio(1);
    mfma16(a, b, acc + 4);
    __builtin_amdgcn_s_setprio(0);
    fence_bar();
}

template<bool OUT_BF16>
__device__ __forceinline__
void gemm256_body(const unsigned short* __restrict__ A,
                  const unsigned short* __restrict__ Bw,
                  const float* __restrict__ bias,
                  unsigned short* __restrict__ outB,
                  float* __restrict__ outF,
                  int M, int N, int K)
{
    __shared__ __align__(16) unsigned short lds[2][2][2][8192];  // 128 KiB

    const int tid  = threadIdx.x;
    const int lane = tid & 63;
    const int wave = tid >> 6;
    const int wm = wave >> 2;          // 0..1: 128-row half of C-tile
    const int wn = wave & 3;           // 0..3: 64-col slice of C-tile

    int bx = blockIdx.x, by = blockIdx.y;
    xcd_remap(bx, by, gridDim.x, gridDim.y);     // T1: L2 locality per XCD
    const int row0 = by * 256;
    const int col0 = bx * 256;

    const int NT = K >> 6;             // K/64 (even: 32 or 64)
    const int G  = NT << 2;

    // staging: thread's linear LDS slot -> inverse-swizzled global source col
    const int srow = tid >> 2;                                  // 0..127 (+128 for j=1)
    const int scol = ((tid & 3) ^ ((tid >> 3) & 3)) * 8;        // inverse st-swizzle
    const unsigned short* Asrc = A  + (size_t)(row0 + srow) * K + scol;
    const unsigned short* Bsrc = Bw + (size_t)(col0 + srow) * K + scol;
    const int sdst = tid * 8;

    // ds_read fragment offsets (swizzled; row bits[2:1] == laneM bits[2:1])
    const int laneM = lane & 15;
    const int laneK = (lane >> 4) * 8;
    const int swz   = ((laneM >> 1) & 3) << 3;
    const int aoff  = (((wm * 128 + laneM) * 32 + laneK)) ^ swz;
    const int boff  = (((wn * 64  + laneM) * 32 + laneK)) ^ swz;

    f32x4 acc[8][4];
#pragma unroll
    for (int i = 0; i < 8; ++i)
#pragma unroll
        for (int j = 0; j < 4; ++j)
            acc[i][j] = (f32x4){0.f, 0.f, 0.f, 0.f};

    // prologue: issue tile0 halves (g0-3) + tile1 A-kh0 (g4); vmcnt(6) retires
    // g0,g1 (tile0 kh0 A+B) leaving 3 halves in flight -> steady state.
    stage_half(0, G, lds, Asrc, Bsrc, K, sdst);
    stage_half(1, G, lds, Asrc, Bsrc, K, sdst);
    stage_half(2, G, lds, Asrc, Bsrc, K, sdst);
    stage_half(3, G, lds, Asrc, Bsrc, K, sdst);
    stage_half(4, G, lds, Asrc, Bsrc, K, sdst);
    wait_vmcnt<6>();
    fence_bar();

    int t = 0;
    for (; t < NT - 2; t += 2) {
        do_tile<0, 6, 6>(t,     G, lds, Asrc, Bsrc, K, sdst, aoff, boff, acc);
        do_tile<1, 6, 6>(t + 1, G, lds, Asrc, Bsrc, K, sdst, aoff, boff, acc);
    }
    // tail: staging stream caps at G -> drain 6 -> 4 -> 0
    do_tile<0, 6, 4>(NT - 2, G, lds, Asrc, Bsrc, K, sdst, aoff, boff, acc);
    do_tile<1, 0, -1>(NT - 1, G, lds, Asrc, Bsrc, K, sdst, aoff, boff, acc);

    // epilogue: C/D layout (verified m89/m91): m-row = (lane>>4)*4 + rr, n-col = lane&15
    const int rQ = (lane >> 4) * 4;
#pragma unroll
    for (int j = 0; j < 4; ++j) {
        const int n = col0 + wn * 64 + j * 16 + laneM;
        const float bv = bias[n];
#pragma unroll
        for (int i = 0; i < 8; ++i) {
#pragma unroll
            for (int rr = 0; rr < 4; ++rr) {
                const int m = row0 + wm * 128 + i * 16 + rQ + rr;
                const float v = acc[i][j][rr] + bv;
                if (OUT_BF16) outB[(size_t)m * N + n] = f2bf(v);
                else          outF[(size_t)m * N + n] = v;
            }
        }
    }
}

__global__ __launch_bounds__(512, 2)
void gemm_u(const unsigned short* __restrict__ A, const unsigned short* __restrict__ Bw,
            const float* __restrict__ bias, unsigned short* __restrict__ outB,
            int M, int N, int K) {
    gemm256_body<true>(A, Bw, bias, outB, nullptr, M, N, K);
}
__global__ __launch_bounds__(512, 2)
void gemm_y(const unsigned short* __restrict__ A, const unsigned short* __restrict__ Bw,
            const float* __restrict__ bias, float* __restrict__ outF,
            int M, int N, int K) {
    gemm256_body<false>(A, Bw, bias, nullptr, outF, M, N, K);
}

// ---------------- segmented-parallel tanh recurrence ----------------
__global__ __launch_bounds__(256)
void recur_seg(const unsigned short* __restrict__ u,
               const float* __restrict__ gamma,
               const float* __restrict__ beta,
               unsigned short* __restrict__ st)
{
    const int tid = blockIdx.x * 256 + threadIdx.x;   // [0, P_*B_*H_)
    const int h   = tid & (H_ - 1);
    const int b   = (tid >> 12) & (B_ - 1);
    const int seg = tid >> 14;
    const int s0  = seg * SEG;
    const int sw  = (seg == 0) ? 0 : s0 - WARM;
    const int nst = s0 + SEG - sw;                    // 128 or 176 (both %16==0)
    const float K2  = 2.885390082f;                   // 2*log2(e)
    const float gk  = gamma[h] * K2;
    const float bek = beta[h]  * K2;
    float state = 0.f;

    size_t idx = ((size_t)b * S_ + sw) * H_ + h;
    float cur[16], nxt[16];
    #pragma unroll
    for (int k = 0; k < 16; ++k) cur[k] = bf2f(u[idx + (size_t)k * H_]);

    int s = sw;
    const int ngroups = nst >> 4;
    for (int g = 0; g < ngroups; ++g) {
        const size_t nidx = idx + (size_t)16 * H_;
        if (g + 1 < ngroups) {
            #pragma unroll
            for (int k = 0; k < 16; ++k) nxt[k] = bf2f(u[nidx + (size_t)k * H_]);
        }
        #pragma unroll
        for (int k = 0; k < 16; ++k) {
            const float c = fmaf(cur[k], K2, bek);    // off-chain
            const float t = fmaf(state, gk, c);       // chain: fma
            const float e = fast_exp2(t);             // chain: v_exp_f32
            const float rr = fast_rcp(1.0f + e);      // chain: add + v_rcp_f32
            state = fmaf(-2.0f, rr, 1.0f);            // chain: fma
            if (s + k >= s0) st[idx + (size_t)k * H_] = f2bf(state);
        }
        idx = nidx; s += 16;
        #pragma unroll
        for (int k = 0; k < 16; ++k) cur[k] = nxt[k];
    }
}

extern "C" void kernel_launch(void* const* d_in, const int* in_sizes, int n_in,
                              void* d_out, int out_size, void* d_ws, size_t ws_size,
                              hipStream_t stream) {
    const float* x     = (const float*)d_in[0];  // [B,S,D]
    const float* W_in  = (const float*)d_in[1];  // [H,D]
    const float* b_in  = (const float*)d_in[2];  // [H]
    const float* W_out = (const float*)d_in[3];  // [D,H]
    const float* b_out = (const float*)d_in[4];  // [D]
    const float* gamma = (const float*)d_in[5];  // [H]
    const float* beta  = (const float*)d_in[6];  // [H]
    float* y = (float*)d_out;                    // [B,S,D] fp32

    // workspace layout (bf16 buffers), total ~192 MiB
    unsigned short* x_b    = (unsigned short*)d_ws;              // M*D
    unsigned short* win_b  = x_b    + (size_t)M_ * D_;           // H*D
    unsigned short* wout_b = win_b  + (size_t)H_ * D_;           // D*H
    unsigned short* u_b    = wout_b + (size_t)D_ * H_;           // M*H
    unsigned short* st_b   = u_b    + (size_t)M_ * H_;           // M*H

    // convert inputs to bf16
    cvt_f32_bf16<<<(M_ * D_) / 2048, 256, 0, stream>>>(x,     x_b,    M_ * D_);
    cvt_f32_bf16<<<(H_ * D_) / 2048, 256, 0, stream>>>(W_in,  win_b,  H_ * D_);
    cvt_f32_bf16<<<(D_ * H_) / 2048, 256, 0, stream>>>(W_out, wout_b, D_ * H_);

    // u = x @ W_in^T + b_in   -> bf16 [M,H]   grid: (cols, rows), 256x256 tiles
    dim3 g1(H_ / 256, M_ / 256);
    gemm_u<<<g1, 512, 0, stream>>>(x_b, win_b, b_in, u_b, M_, H_, D_);

    // segmented-parallel recurrence -> states bf16 [M,H]
    recur_seg<<<(P_ * B_ * H_) / 256, 256, 0, stream>>>(u_b, gamma, beta, st_b);

    // y = states @ W_out^T + b_out -> fp32 [M,D]   grid: (cols, rows)
    dim3 g2(D_ / 256, M_ / 256);
    gemm_y<<<g2, 512, 0, stream>>>(st_b, wout_b, b_out, y, M_, D_, H_);
}

// Round 7
// 458.769 us; speedup vs baseline: 1.2419x; 1.0551x over previous
//
#include <hip/hip_runtime.h>
#include <hip/hip_bf16.h>
#include <math.h>

// Problem constants (from reference)
#define B_ 4
#define S_ 2048
#define D_ 2048
#define H_ 4096
#define M_ (B_*S_)   // 8192 rows for both GEMMs

// Segmented recurrence: 16 segments x 128 steps, 48-step warmup.
#define SEG 128
#define WARM 48
#define P_ (S_/SEG)   // 16

typedef __bf16 bf16x8 __attribute__((ext_vector_type(8)));
typedef float f32x4 __attribute__((ext_vector_type(4)));

__device__ __forceinline__ float bf2f(unsigned short v) {
    union { unsigned u; float f; } x; x.u = ((unsigned)v) << 16; return x.f;
}
__device__ __forceinline__ unsigned short f2bf(float f) {
    union { float f; unsigned u; } x; x.f = f;
    unsigned u = x.u;
    unsigned r = (u + 0x7fffu + ((u >> 16) & 1u)) >> 16;  // RNE
    return (unsigned short)r;
}

__device__ __forceinline__ float fast_exp2(float x) {
#if __has_builtin(__builtin_amdgcn_exp2f)
    return __builtin_amdgcn_exp2f(x);
#else
    return __builtin_exp2f(x);
#endif
}
__device__ __forceinline__ float fast_rcp(float x) {
    return __builtin_amdgcn_rcpf(x);
}

// ---------------- fp32 -> bf16 conversion (8 elems/thread) ----------------
__global__ void cvt_f32_bf16(const float* __restrict__ in,
                             unsigned short* __restrict__ out, int n) {
    int i = (blockIdx.x * blockDim.x + threadIdx.x) * 8;
    if (i >= n) return;
    float4 a = *(const float4*)(in + i);
    float4 b = *(const float4*)(in + i + 4);
    ushort4 o0; o0.x = f2bf(a.x); o0.y = f2bf(a.y); o0.z = f2bf(a.z); o0.w = f2bf(a.w);
    ushort4 o1; o1.x = f2bf(b.x); o1.y = f2bf(b.y); o1.z = f2bf(b.z); o1.w = f2bf(b.w);
    *(ushort4*)(out + i) = o0;
    *(ushort4*)(out + i + 4) = o1;
}

// ---------------- async global->LDS 16B copy ----------------
__device__ __forceinline__ void async_cp16(const unsigned short* g, unsigned short* l) {
    __builtin_amdgcn_global_load_lds(
        (__attribute__((address_space(1))) void*)g,
        (__attribute__((address_space(3))) void*)l,
        16, 0, 0);
}

// Raw barrier with compiler-only memory fence. NO sched_barrier (R3 A/B:
// sched pinning regressed, m141-like).
__device__ __forceinline__ void fence_bar() {
    asm volatile("" ::: "memory");
    __builtin_amdgcn_s_barrier();
    asm volatile("" ::: "memory");
}

template<int N>
__device__ __forceinline__ void wait_vmcnt() {
    if constexpr (N == 0)      asm volatile("s_waitcnt vmcnt(0)" ::: "memory");
    else if constexpr (N == 2) asm volatile("s_waitcnt vmcnt(2)" ::: "memory");
    else if constexpr (N == 4) asm volatile("s_waitcnt vmcnt(4)" ::: "memory");
    else if constexpr (N == 6) asm volatile("s_waitcnt vmcnt(6)" ::: "memory");
}

// ---------------- 256x256 GEMM, 4-quadrant phases (B^T layout) ----------------
// C[m,n] = sum_k A[m,k]*Bw[n,k] + bias[n]
// LDS: [buf][mat(A/B)][Mhalf][128 rows x 64 K shorts] = 8 regions x 16KB = 128 KiB.
// Phases per K-tile (BK=64), each = one C-quadrant, 16 MFMA:
//   P0: read A0-3 + B0-1 (12 ds_read_b128); ISSUE ALL 4 units of tile t+1
//   P1: read B2-3 (4)
//   P2: read A4-7 (8)
//   P3: no reads; wait vmcnt(0)  <- retires tile t+1's 8 loads (issued 3
//       phases ago ~1000cy, past HBM latency -> stall-free; nothing newer
//       is in flight, so a counted wait would be identical)
// R6 BUG FIXED HERE: with M-half regions, region choice is per-WAVE (wm/bh2),
// so ALL FOUR regions are read at P0 by some wave. R6's spread waits
// (vmcnt(6)@P1 etc.) left B-hi/A-hi un-retired at P0 -> race, absmax 1.57.
// Now: all units of tile t are retired by t-1's P3 vmcnt(0) + barrier,
// >= 2 barriers before any tile-t ds_read. WAR: buf[(t+1)&1]'s previous
// occupant (t-1) had all ds_reads lgkm-forced before t-1 P2's MFMA, >= 2
// barriers before t P0's stage writes can issue. Uniform template; staging
// guard (u>=G) handles the last tile; accumulation order identical to R1.
// Swizzle (row stride = 128B = bank wrap): 16B-granule g' = g ^ (row&7);
// inverse permutation on the gload SOURCE col (rule #21); ds_read applies
// the same XOR. 8-granule spread -> 2 lanes/bank (free).
// LDS-BW roofline for this config: 256KB/K-tile/CU ~= 1000cy vs 620cy MFMA
// -> ~62% MfmaUtil ceiling (= m201's measured 62.1%).

__device__ __forceinline__
void stage_unit(int u, int G, unsigned short (&lds)[2][2][2][8192],
                const unsigned short* Asrc, const unsigned short* Bsrc,
                int K, int sdst)
{
    if (u >= G) return;
    const int tau = u >> 2;
    const int q   = u & 3;                    // 0:A-lo 1:B-lo 2:B-hi 3:A-hi
    const int mat = (q ^ (q >> 1)) & 1;
    const int mh  = q >> 1;
    const unsigned short* src = (mat ? Bsrc : Asrc) + (size_t)(mh * 128) * K + tau * 64;
    unsigned short* dst = &lds[tau & 1][mat][mh][sdst];
    async_cp16(src, dst);
    async_cp16(src + (size_t)64 * K, dst + 4096);
}

// One K-tile = 4 quadrant-phases; 2 barriers/phase (R1-verified sync skeleton).
template<int BUF>
__device__ __forceinline__
void do_tile(int t, int G, unsigned short (&lds)[2][2][2][8192],
             const unsigned short* Asrc, const unsigned short* Bsrc, int K,
             int sdst, int wm, int bh2, int abase, int bbase, int p0, int p1,
             f32x4 (*acc)[4])
{
    const unsigned short* RA = &lds[BUF][0][wm][0];
    const unsigned short* RB = &lds[BUF][1][bh2][0];
    const int u0 = 4 * (t + 1);
    bf16x8 a[4][2], bl[2][2], bh[2][2];

    // ---- P0: quadrant (A0-3, B0-1); issue ALL of tile t+1's staging ----
#pragma unroll
    for (int i = 0; i < 4; ++i) {
        a[i][0] = *(const bf16x8*)(RA + abase + i * 1024 + p0);
        a[i][1] = *(const bf16x8*)(RA + abase + i * 1024 + p1);
    }
#pragma unroll
    for (int j = 0; j < 2; ++j) {
        bl[j][0] = *(const bf16x8*)(RB + bbase + j * 1024 + p0);
        bl[j][1] = *(const bf16x8*)(RB + bbase + j * 1024 + p1);
    }
    stage_unit(u0 + 0, G, lds, Asrc, Bsrc, K, sdst);
    stage_unit(u0 + 1, G, lds, Asrc, Bsrc, K, sdst);
    stage_unit(u0 + 2, G, lds, Asrc, Bsrc, K, sdst);
    stage_unit(u0 + 3, G, lds, Asrc, Bsrc, K, sdst);
    fence_bar();
    __builtin_amdgcn_s_setprio(1);
#pragma unroll
    for (int i = 0; i < 4; ++i)
#pragma unroll
        for (int j = 0; j < 2; ++j) {
            acc[i][j] = __builtin_amdgcn_mfma_f32_16x16x32_bf16(a[i][0], bl[j][0], acc[i][j], 0, 0, 0);
            acc[i][j] = __builtin_amdgcn_mfma_f32_16x16x32_bf16(a[i][1], bl[j][1], acc[i][j], 0, 0, 0);
        }
    __builtin_amdgcn_s_setprio(0);
    fence_bar();

    // ---- P1: quadrant (A0-3, B2-3) ----
#pragma unroll
    for (int j = 0; j < 2; ++j) {
        bh[j][0] = *(const bf16x8*)(RB + bbase + (j + 2) * 1024 + p0);
        bh[j][1] = *(const bf16x8*)(RB + bbase + (j + 2) * 1024 + p1);
    }
    fence_bar();
    __builtin_amdgcn_s_setprio(1);
#pragma unroll
    for (int i = 0; i < 4; ++i)
#pragma unroll
        for (int j = 0; j < 2; ++j) {
            acc[i][j + 2] = __builtin_amdgcn_mfma_f32_16x16x32_bf16(a[i][0], bh[j][0], acc[i][j + 2], 0, 0, 0);
            acc[i][j + 2] = __builtin_amdgcn_mfma_f32_16x16x32_bf16(a[i][1], bh[j][1], acc[i][j + 2], 0, 0, 0);
        }
    __builtin_amdgcn_s_setprio(0);
    fence_bar();

    // ---- P2: quadrant (A4-7, B0-1) ----
#pragma unroll
    for (int i = 0; i < 4; ++i) {
        a[i][0] = *(const bf16x8*)(RA + abase + (i + 4) * 1024 + p0);
        a[i][1] = *(const bf16x8*)(RA + abase + (i + 4) * 1024 + p1);
    }
    fence_bar();
    __builtin_amdgcn_s_setprio(1);
#pragma unroll
    for (int i = 0; i < 4; ++i)
#pragma unroll
        for (int j = 0; j < 2; ++j) {
            acc[i + 4][j] = __builtin_amdgcn_mfma_f32_16x16x32_bf16(a[i][0], bl[j][0], acc[i + 4][j], 0, 0, 0);
            acc[i + 4][j] = __builtin_amdgcn_mfma_f32_16x16x32_bf16(a[i][1], bl[j][1], acc[i + 4][j], 0, 0, 0);
        }
    __builtin_amdgcn_s_setprio(0);
    fence_bar();

    // ---- P3: quadrant (A4-7, B2-3); drain tile t+1's staging (stall-free) ----
    wait_vmcnt<0>();
    fence_bar();
    __builtin_amdgcn_s_setprio(1);
#pragma unroll
    for (int i = 0; i < 4; ++i)
#pragma unroll
        for (int j = 0; j < 2; ++j) {
            acc[i + 4][j + 2] = __builtin_amdgcn_mfma_f32_16x16x32_bf16(a[i][0], bh[j][0], acc[i + 4][j + 2], 0, 0, 0);
            acc[i + 4][j + 2] = __builtin_amdgcn_mfma_f32_16x16x32_bf16(a[i][1], bh[j][1], acc[i + 4][j + 2], 0, 0, 0);
        }
    __builtin_amdgcn_s_setprio(0);
    fence_bar();
}

template<bool OUT_BF16>
__device__ __forceinline__
void gemm256_body(const unsigned short* __restrict__ A,
                  const unsigned short* __restrict__ Bw,
                  const float* __restrict__ bias,
                  unsigned short* __restrict__ outB,
                  float* __restrict__ outF,
                  int M, int N, int K)
{
    __shared__ __align__(16) unsigned short lds[2][2][2][8192];  // 128 KiB

    const int tid  = threadIdx.x;
    const int lane = tid & 63;
    const int wave = tid >> 6;
    const int wm = wave >> 2;          // 0..1: 128-row half of C-tile (A region half)
    const int wn = wave & 3;           // 0..3: 64-col slice (B half = wn>>1)
    const int row0 = blockIdx.y * 256;
    const int col0 = blockIdx.x * 256;
    const int NT = K >> 6;             // K/64 (even: 32 or 64)
    const int G  = NT << 2;            // staging units

    // staging: thread t writes region shorts [t*8] and [t*8+4096] (linear);
    // source carries inverse granule swizzle: granule = (t&7) ^ (row&7)
    const int srow = tid >> 3;                                  // 0..63 (+64 for 2nd)
    const int scol = ((tid & 7) ^ ((tid >> 3) & 7)) * 8;
    const unsigned short* Asrc = A  + (size_t)(row0 + srow) * K + scol;
    const unsigned short* Bsrc = Bw + (size_t)(col0 + srow) * K + scol;
    const int sdst = tid * 8;

    // ds_read offsets within a [128][64] region (swizzled granule):
    // idx(lr, ks) = lr*64 + (((ks*4 + (lane>>4)) ^ (lr&7)) << 3); lr&7 == laneM&7
    const int laneM = lane & 15;
    const int g4    = lane >> 4;
    const int p0 = ((g4)     ^ (laneM & 7)) << 3;
    const int p1 = ((g4 + 4) ^ (laneM & 7)) << 3;
    const int abase = laneM * 64;
    const int bbase = (wn & 1) * 4096 + laneM * 64;
    const int bh2   = wn >> 1;

    f32x4 acc[8][4];
#pragma unroll
    for (int i = 0; i < 8; ++i)
#pragma unroll
        for (int j = 0; j < 4; ++j)
            acc[i][j] = (f32x4){0.f, 0.f, 0.f, 0.f};

    // prologue: stage tile0's 4 units; drain; barrier -> tile0 fully valid.
    stage_unit(0, G, lds, Asrc, Bsrc, K, sdst);
    stage_unit(1, G, lds, Asrc, Bsrc, K, sdst);
    stage_unit(2, G, lds, Asrc, Bsrc, K, sdst);
    stage_unit(3, G, lds, Asrc, Bsrc, K, sdst);
    wait_vmcnt<0>();
    fence_bar();

    for (int t = 0; t < NT; t += 2) {
        do_tile<0>(t,     G, lds, Asrc, Bsrc, K, sdst, wm, bh2, abase, bbase, p0, p1, acc);
        do_tile<1>(t + 1, G, lds, Asrc, Bsrc, K, sdst, wm, bh2, abase, bbase, p0, p1, acc);
    }

    // epilogue: C/D layout (verified m89/m91): m-row = (lane>>4)*4 + rr, n-col = lane&15
    const int rQ = (lane >> 4) * 4;
#pragma unroll
    for (int j = 0; j < 4; ++j) {
        const int n = col0 + wn * 64 + j * 16 + laneM;
        const float bv = bias[n];
#pragma unroll
        for (int i = 0; i < 8; ++i) {
#pragma unroll
            for (int rr = 0; rr < 4; ++rr) {
                const int m = row0 + wm * 128 + i * 16 + rQ + rr;
                const float v = acc[i][j][rr] + bv;
                if (OUT_BF16) outB[(size_t)m * N + n] = f2bf(v);
                else          outF[(size_t)m * N + n] = v;
            }
        }
    }
}

__global__ __launch_bounds__(512, 2)
void gemm_u(const unsigned short* __restrict__ A, const unsigned short* __restrict__ Bw,
            const float* __restrict__ bias, unsigned short* __restrict__ outB,
            int M, int N, int K) {
    gemm256_body<true>(A, Bw, bias, outB, nullptr, M, N, K);
}
__global__ __launch_bounds__(512, 2)
void gemm_y(const unsigned short* __restrict__ A, const unsigned short* __restrict__ Bw,
            const float* __restrict__ bias, float* __restrict__ outF,
            int M, int N, int K) {
    gemm256_body<false>(A, Bw, bias, nullptr, outF, M, N, K);
}

// ---------------- segmented-parallel tanh recurrence ----------------
__global__ __launch_bounds__(256)
void recur_seg(const unsigned short* __restrict__ u,
               const float* __restrict__ gamma,
               const float* __restrict__ beta,
               unsigned short* __restrict__ st)
{
    const int tid = blockIdx.x * 256 + threadIdx.x;   // [0, P_*B_*H_)
    const int h   = tid & (H_ - 1);
    const int b   = (tid >> 12) & (B_ - 1);
    const int seg = tid >> 14;
    const int s0  = seg * SEG;
    const int sw  = (seg == 0) ? 0 : s0 - WARM;
    const int nst = s0 + SEG - sw;                    // 128 or 176 (both %16==0)
    const float K2  = 2.885390082f;                   // 2*log2(e)
    const float gk  = gamma[h] * K2;
    const float bek = beta[h]  * K2;
    float state = 0.f;

    size_t idx = ((size_t)b * S_ + sw) * H_ + h;
    float cur[16], nxt[16];
    #pragma unroll
    for (int k = 0; k < 16; ++k) cur[k] = bf2f(u[idx + (size_t)k * H_]);

    int s = sw;
    const int ngroups = nst >> 4;
    for (int g = 0; g < ngroups; ++g) {
        const size_t nidx = idx + (size_t)16 * H_;
        if (g + 1 < ngroups) {
            #pragma unroll
            for (int k = 0; k < 16; ++k) nxt[k] = bf2f(u[nidx + (size_t)k * H_]);
        }
        #pragma unroll
        for (int k = 0; k < 16; ++k) {
            const float c = fmaf(cur[k], K2, bek);    // off-chain
            const float t = fmaf(state, gk, c);       // chain: fma
            const float e = fast_exp2(t);             // chain: v_exp_f32
            const float rr = fast_rcp(1.0f + e);      // chain: add + v_rcp_f32
            state = fmaf(-2.0f, rr, 1.0f);            // chain: fma
            if (s + k >= s0) st[idx + (size_t)k * H_] = f2bf(state);
        }
        idx = nidx; s += 16;
        #pragma unroll
        for (int k = 0; k < 16; ++k) cur[k] = nxt[k];
    }
}

extern "C" void kernel_launch(void* const* d_in, const int* in_sizes, int n_in,
                              void* d_out, int out_size, void* d_ws, size_t ws_size,
                              hipStream_t stream) {
    const float* x     = (const float*)d_in[0];  // [B,S,D]
    const float* W_in  = (const float*)d_in[1];  // [H,D]
    const float* b_in  = (const float*)d_in[2];  // [H]
    const float* W_out = (const float*)d_in[3];  // [D,H]
    const float* b_out = (const float*)d_in[4];  // [D]
    const float* gamma = (const float*)d_in[5];  // [H]
    const float* beta  = (const float*)d_in[6];  // [H]
    float* y = (float*)d_out;                    // [B,S,D] fp32

    // workspace layout (bf16 buffers), total ~192 MiB
    unsigned short* x_b    = (unsigned short*)d_ws;              // M*D
    unsigned short* win_b  = x_b    + (size_t)M_ * D_;           // H*D
    unsigned short* wout_b = win_b  + (size_t)H_ * D_;           // D*H
    unsigned short* u_b    = wout_b + (size_t)D_ * H_;           // M*H
    unsigned short* st_b   = u_b    + (size_t)M_ * H_;           // M*H

    // convert inputs to bf16
    cvt_f32_bf16<<<(M_ * D_) / 2048, 256, 0, stream>>>(x,     x_b,    M_ * D_);
    cvt_f32_bf16<<<(H_ * D_) / 2048, 256, 0, stream>>>(W_in,  win_b,  H_ * D_);
    cvt_f32_bf16<<<(D_ * H_) / 2048, 256, 0, stream>>>(W_out, wout_b, D_ * H_);

    // u = x @ W_in^T + b_in   -> bf16 [M,H]   grid: (cols, rows), 256x256 tiles
    dim3 g1(H_ / 256, M_ / 256);
    gemm_u<<<g1, 512, 0, stream>>>(x_b, win_b, b_in, u_b, M_, H_, D_);

    // segmented-parallel recurrence -> states bf16 [M,H]
    recur_seg<<<(P_ * B_ * H_) / 256, 256, 0, stream>>>(u_b, gamma, beta, st_b);

    // y = states @ W_out^T + b_out -> fp32 [M,D]   grid: (cols, rows)
    dim3 g2(D_ / 256, M_ / 256);
    gemm_y<<<g2, 512, 0, stream>>>(st_b, wout_b, b_out, y, M_, D_, H_);
}